// Round 6
// baseline (527.214 us; speedup 1.0000x reference)
//
#include <hip/hip_runtime.h>
#include <hip/hip_bf16.h>

#define B_ 8
#define C_ 1536
#define T_ 4096
#define A_ 128
#define K3_ 4608        // 3*C columns of W1
#define M16_ 256        // T / 16 chunks (carry granularity)
#define SCW_ 104        // k2h scratch row stride (f16), 16B-aligned

typedef _Float16 h8  __attribute__((ext_vector_type(8)));
typedef float    f4  __attribute__((ext_vector_type(4)));

// ---------------- kernel 0: W1 fp32 -> f16, MFMA A-fragment order -----------
// W1f[((kb*8 + t8)*64 + lane)*8 + j] = W1[a=t8*16+(lane&15)][k=kb*32+(lane>>4)*8+j]
__global__ void k0_pack(const float* __restrict__ W1, _Float16* __restrict__ W1f) {
    int i = blockIdx.x * 256 + threadIdx.x;
    if (i >= A_ * K3_) return;
    int a = i / K3_, k = i - a * K3_;
    int t8 = a >> 4, r15 = a & 15;
    int kb = k >> 5, q = (k >> 3) & 3, j = k & 7;
    int lane = q * 16 + r15;
    W1f[(size_t)((kb * 8 + t8) * 64 + lane) * 8 + j] = (_Float16)W1[i];
}

// ---------------- kernel 1: 16-t-granular carries -> carryT[b][m16][c] ------
// 2 rows per wave (independent scan chains -> 2x ILP on the shfl chain).
// 16-t groups = 4 lanes; float4 store covers both rows (contiguous in c).
__global__ __launch_bounds__(256) void k1_carryT(
    const float* __restrict__ x, const int* __restrict__ lens,
    float2* __restrict__ carryT)
{
    const int pid  = blockIdx.x * 4 + (threadIdx.x >> 6);  // row-pair 0..6143
    const int lane = threadIdx.x & 63;
    const int b    = pid / 768;
    const int c0   = (pid - b * 768) * 2;
    const int len  = lens[b];
    const float* xr0 = x + ((size_t)b * C_ + c0) * T_;
    const float* xr1 = xr0 + T_;
    float2* ct = carryT + (size_t)b * M16_ * C_ + c0;
    const int grp = lane >> 2;           // 16-t group 0..15 within 256-t g
    float bA1 = 0.f, bA2 = 0.f, bB1 = 0.f, bB2 = 0.f;
#pragma unroll
    for (int g = 0; g < 16; ++g) {
        const int t0g = g * 256;
        if (t0g >= len) {
            if ((lane & 3) == 0) {
                float4 st = {bA1, bA2, bB1, bB2};
                *(float4*)&ct[(size_t)(g * 16 + grp) * C_] = st;
            }
            continue;
        }
        float4 va = *(const float4*)(xr0 + t0g + lane * 4);
        float4 vb = *(const float4*)(xr1 + t0g + lane * 4);
        float sA1, sA2, sB1, sB2;
        if (t0g + 256 <= len) {
            sA1 = (va.x + va.y) + (va.z + va.w);
            sA2 = (va.x * va.x + va.y * va.y) + (va.z * va.z + va.w * va.w);
            sB1 = (vb.x + vb.y) + (vb.z + vb.w);
            sB2 = (vb.x * vb.x + vb.y * vb.y) + (vb.z * vb.z + vb.w * vb.w);
        } else {
            const int tbase = t0g + lane * 4;
            float av[4] = {va.x, va.y, va.z, va.w};
            float bv[4] = {vb.x, vb.y, vb.z, vb.w};
            sA1 = sA2 = sB1 = sB2 = 0.f;
#pragma unroll
            for (int j = 0; j < 4; ++j) {
                bool in = (tbase + j) < len;
                float ma = in ? av[j] : 0.f;
                float mb = in ? bv[j] : 0.f;
                sA1 += ma; sA2 += ma * av[j];
                sB1 += mb; sB2 += mb * bv[j];
            }
        }
        // 4-lane group totals (d=1,2)
        sA1 += __shfl_xor(sA1, 1, 64); sA2 += __shfl_xor(sA2, 1, 64);
        sB1 += __shfl_xor(sB1, 1, 64); sB2 += __shfl_xor(sB2, 1, 64);
        sA1 += __shfl_xor(sA1, 2, 64); sA2 += __shfl_xor(sA2, 2, 64);
        sB1 += __shfl_xor(sB1, 2, 64); sB2 += __shfl_xor(sB2, 2, 64);
        // inclusive scan over 16 groups (stride-4 Hillis-Steele)
        float VA1 = sA1, VA2 = sA2, VB1 = sB1, VB2 = sB2;
#pragma unroll
        for (int d = 4; d < 64; d <<= 1) {
            float oA1 = __shfl_up(VA1, d, 64);
            float oA2 = __shfl_up(VA2, d, 64);
            float oB1 = __shfl_up(VB1, d, 64);
            float oB2 = __shfl_up(VB2, d, 64);
            if (lane >= d) { VA1 += oA1; VA2 += oA2; VB1 += oB1; VB2 += oB2; }
        }
        if ((lane & 3) == 0) {
            float4 st = {bA1 + VA1 - sA1, bA2 + VA2 - sA2,
                         bB1 + VB1 - sB1, bB2 + VB2 - sB2};
            *(float4*)&ct[(size_t)(g * 16 + grp) * C_] = st;
        }
        bA1 += __shfl(VA1, 63, 64);
        bA2 += __shfl(VA2, 63, 64);
        bB1 += __shfl(VB1, 63, 64);
        bB2 += __shfl(VB2, 63, 64);
    }
}

// ---------------- kernel 2h: fused stats+GEMM, wave-owns-output -------------
// grid 512 = (b, 64-t). 4 waves x 16 t each; wave covers ALL K (48 c-steps)
// -> acc 32 AGPR + ~70 VGPR <= 128-reg HW granule -> 4 waves/SIMD.
// No split-K reduce, no main-loop barriers. Lane = (channel kc, 8-t half th).
// Fast paths: full (no masks), beyond-len (constant mn/sd). rn hoisted.
// LDS k-block XOR swizzle kills the th0/th1 4-way write conflict.
__global__ __launch_bounds__(256, 4) void k2h(
    const float* __restrict__ x, const int* __restrict__ lens,
    const float2* __restrict__ carryT, const _Float16* __restrict__ W1f,
    const float* __restrict__ b1, const float* __restrict__ W2,
    float* __restrict__ logits)
{
    __shared__ _Float16 sc_all[4 * 16 * SCW_];   // 13.3 KB
    __shared__ float s_b1[A_], s_w2[A_];

    const int tid = threadIdx.x, lane = tid & 63, w = tid >> 6;
    const int bid = blockIdx.x;
    const int b   = bid >> 6;
    const int t0w = (bid & 63) * 64 + w * 16;    // wave's 16-t window
    const int m16 = t0w >> 4;
    const int len = lens[b];
    if (tid < A_) { s_b1[tid] = b1[tid]; s_w2[tid] = W2[tid]; }
    __syncthreads();

    const int kc = lane >> 1;            // channel within 32-group
    const int th = lane & 1;             // 8-t half
    const int tb = t0w + th * 8;
    _Float16* sc = sc_all + w * (16 * SCW_);
    // swizzled write column: k-block (kc>>3) XOR'd with th<<1
    const int kcol = (((kc >> 3) ^ (th << 1)) << 3) + (kc & 7);
    _Float16* scw = sc + th * 8 * SCW_ + kcol;
    const h8* W1f8 = (const h8*)W1f;

    const bool beyond = t0w >= len;              // wave-uniform
    const bool full   = (t0w + 16) <= len;       // wave-uniform

    float rn_l[8];
#pragma unroll
    for (int j = 0; j < 8; ++j)
        rn_l[j] = __builtin_amdgcn_rcpf((float)min(tb + j + 1, len));

    f4 acc[8] = {};
    const float* xptr = x + ((size_t)b * C_ + kc) * T_ + tb;
    const float2* crp = carryT + ((size_t)b * M16_ + m16) * C_ + kc;

    const int t15 = lane & 15, k8 = lane >> 4;
    const int rdbase = t15 * SCW_ + ((k8 ^ ((t15 >> 3) << 1)) << 3);

    for (int step = 0; step < 48; ++step) {
        float4 xa = ((const float4*)xptr)[0];
        float4 xb = ((const float4*)xptr)[1];
        xptr += 32 * (size_t)T_;
        const float2 cr = crp[(size_t)step * 32];
        float xs[8] = {xa.x, xa.y, xa.z, xa.w, xb.x, xb.y, xb.z, xb.w};

        if (beyond) {
            // stats constant for t >= len
            const float rn0 = rn_l[0];           // = 1/len
            const float mn = cr.x * rn0;
            const float sd = sqrtf(fmaxf(cr.y * rn0 - mn * mn, 1e-12f));
            const _Float16 hm = (_Float16)mn, hs = (_Float16)sd;
#pragma unroll
            for (int j = 0; j < 8; ++j) {
                scw[j * SCW_]      = (_Float16)xs[j];
                scw[j * SCW_ + 32] = hm;
                scw[j * SCW_ + 64] = hs;
            }
        } else {
            float ls1 = 0.f, ls2 = 0.f;
            if (full) {
#pragma unroll
                for (int j = 0; j < 8; ++j) { ls1 += xs[j]; ls2 += xs[j] * xs[j]; }
            } else {
#pragma unroll
                for (int j = 0; j < 8; ++j) {
                    float mv = (tb + j < len) ? xs[j] : 0.f;
                    ls1 += mv; ls2 += mv * xs[j];
                }
            }
            const float o1 = __shfl_xor(ls1, 1, 64);
            const float o2 = __shfl_xor(ls2, 1, 64);
            float r1 = cr.x + (th ? o1 : 0.f);
            float r2 = cr.y + (th ? o2 : 0.f);
            if (full) {
#pragma unroll
                for (int j = 0; j < 8; ++j) {
                    const float xval = xs[j];
                    r1 += xval; r2 += xval * xval;
                    const float mn = r1 * rn_l[j];
                    const float sd = sqrtf(fmaxf(r2 * rn_l[j] - mn * mn, 1e-12f));
                    scw[j * SCW_]      = (_Float16)xval;
                    scw[j * SCW_ + 32] = (_Float16)mn;
                    scw[j * SCW_ + 64] = (_Float16)sd;
                }
            } else {
#pragma unroll
                for (int j = 0; j < 8; ++j) {
                    const float xval = xs[j];
                    const float mv = (tb + j < len) ? xval : 0.f;
                    r1 += mv; r2 += mv * xval;
                    const float mn = r1 * rn_l[j];
                    const float sd = sqrtf(fmaxf(r2 * rn_l[j] - mn * mn, 1e-12f));
                    scw[j * SCW_]      = (_Float16)xval;
                    scw[j * SCW_ + 32] = (_Float16)mn;
                    scw[j * SCW_ + 64] = (_Float16)sd;
                }
            }
        }
        // within-wave LDS ordering via lgkmcnt; no barrier needed
#pragma unroll
        for (int p = 0; p < 3; ++p) {
            h8 bf = *(const h8*)&sc[rdbase + p * 32];
            const int kb = p * 48 + step;
#pragma unroll
            for (int ii = 0; ii < 8; ++ii) {
                h8 af = W1f8[(size_t)(kb * 8 + ii) * 64 + lane];
                acc[ii] = __builtin_amdgcn_mfma_f32_16x16x32_f16(af, bf, acc[ii], 0, 0, 0);
            }
        }
    }

    // per-wave epilogue: tanh + W2 dot, no cross-wave reduce needed
    const int q = lane >> 4;
    float pr = 0.f;
#pragma unroll
    for (int ii = 0; ii < 8; ++ii)
#pragma unroll
        for (int rg = 0; rg < 4; ++rg) {
            const int a = ii * 16 + q * 4 + rg;
            pr += tanhf(acc[ii][rg] + s_b1[a]) * s_w2[a];
        }
    pr += __shfl_xor(pr, 16, 64);
    pr += __shfl_xor(pr, 32, 64);
    if (lane < 16)
        logits[(size_t)b * T_ + t0w + t15] = pr;
}

// ---------------- kernel 3: softmax prep (e, cumsum Z) per b ----------------
// b2 and the max-subtraction cancel in the e/Z ratios used downstream.
__global__ __launch_bounds__(1024) void k3_softmax(
    const float* __restrict__ logits, float* __restrict__ earr,
    float* __restrict__ zarr)
{
    __shared__ float wsum[16];
    const int b = blockIdx.x, tid = threadIdx.x, lane = tid & 63, w = tid >> 6;
    float4 v = *(const float4*)(logits + (size_t)b * T_ + tid * 4);
    float e0 = expf(v.x), e1 = expf(v.y), e2 = expf(v.z), e3 = expf(v.w);
    float s = (e0 + e1) + (e2 + e3);
    float V = s;
#pragma unroll
    for (int d = 1; d < 64; d <<= 1) {
        float o = __shfl_up(V, d, 64);
        if (lane >= d) V += o;
    }
    if (lane == 63) wsum[w] = V;
    __syncthreads();
    float wb = 0.f;
#pragma unroll
    for (int i = 0; i < 16; ++i) wb += (i < w) ? wsum[i] : 0.f;
    float run = wb + (V - s);
    float4 ev, zv;
    ev.x = e0; run += e0; zv.x = run;
    ev.y = e1; run += e1; zv.y = run;
    ev.z = e2; run += e2; zv.z = run;
    ev.w = e3; run += e3; zv.w = run;
    *(float4*)(earr + (size_t)b * T_ + tid * 4) = ev;
    *(float4*)(zarr + (size_t)b * T_ + tid * 4) = zv;
}

// ---------------- kernel 4: weighted running mean/std, 2 rows/wave ----------
// e/z loads and rcp(z) shared across the row pair; two independent scan
// chains interleave -> 2x ILP on the shfl-dependent critical path.
__global__ __launch_bounds__(256) void k4_wstats(
    const float* __restrict__ x, const float* __restrict__ earr,
    const float* __restrict__ zarr, float* __restrict__ out)
{
    const int pid  = blockIdx.x * 4 + (threadIdx.x >> 6);  // row-pair
    const int lane = threadIdx.x & 63;
    const int b = pid / 768;
    const int c = (pid - b * 768) * 2;
    const float* xr0 = x + ((size_t)b * C_ + c) * T_;
    const float* xr1 = xr0 + T_;
    const float* er = earr + (size_t)b * T_;
    const float* zr = zarr + (size_t)b * T_;
    float am0 = 0.f, asd0 = 0.f, am1 = 0.f, asd1 = 0.f;
    float bS0 = 0.f, bD0 = 0.f, bS1 = 0.f, bD1 = 0.f;
#pragma unroll 4
    for (int g = 0; g < 16; ++g) {
        const int off = g * 256 + lane * 4;
        float4 ev = *(const float4*)(er + off);
        float4 zv = *(const float4*)(zr + off);
        float4 xa = *(const float4*)(xr0 + off);
        float4 xb = *(const float4*)(xr1 + off);
        // S prefixes (both rows)
        float sA0 = ev.x * xa.x;
        float sA1 = sA0 + ev.y * xa.y;
        float sA2 = sA1 + ev.z * xa.z;
        float sA3 = sA2 + ev.w * xa.w;
        float sB0 = ev.x * xb.x;
        float sB1 = sB0 + ev.y * xb.y;
        float sB2 = sB1 + ev.z * xb.z;
        float sB3 = sB2 + ev.w * xb.w;
        float VA = sA3, VB = sB3;
#pragma unroll
        for (int d = 1; d < 64; d <<= 1) {
            float oA = __shfl_up(VA, d, 64);
            float oB = __shfl_up(VB, d, 64);
            if (lane >= d) { VA += oA; VB += oB; }
        }
        const float SxA = bS0 + (VA - sA3);
        const float SxB = bS1 + (VB - sB3);
        bS0 += __shfl(VA, 63, 64);
        bS1 += __shfl(VB, 63, 64);
        const float rz0 = __builtin_amdgcn_rcpf(zv.x);
        const float rz1 = __builtin_amdgcn_rcpf(zv.y);
        const float rz2 = __builtin_amdgcn_rcpf(zv.z);
        const float rz3 = __builtin_amdgcn_rcpf(zv.w);
        const float wmA0 = (SxA + sA0) * rz0, wmA1 = (SxA + sA1) * rz1;
        const float wmA2 = (SxA + sA2) * rz2, wmA3 = (SxA + sA3) * rz3;
        const float wmB0 = (SxB + sB0) * rz0, wmB1 = (SxB + sB1) * rz1;
        const float wmB2 = (SxB + sB2) * rz2, wmB3 = (SxB + sB3) * rz3;
        am0 += (wmA0 + wmA1) + (wmA2 + wmA3);
        am1 += (wmB0 + wmB1) + (wmB2 + wmB3);
        const float dA0 = xa.x - wmA0, dA1 = xa.y - wmA1;
        const float dA2 = xa.z - wmA2, dA3 = xa.w - wmA3;
        const float dB0 = xb.x - wmB0, dB1 = xb.y - wmB1;
        const float dB2 = xb.z - wmB2, dB3 = xb.w - wmB3;
        float qA0 = ev.x * dA0 * dA0;
        float qA1 = qA0 + ev.y * dA1 * dA1;
        float qA2 = qA1 + ev.z * dA2 * dA2;
        float qA3 = qA2 + ev.w * dA3 * dA3;
        float qB0 = ev.x * dB0 * dB0;
        float qB1 = qB0 + ev.y * dB1 * dB1;
        float qB2 = qB1 + ev.z * dB2 * dB2;
        float qB3 = qB2 + ev.w * dB3 * dB3;
        float WA = qA3, WB = qB3;
#pragma unroll
        for (int d = 1; d < 64; d <<= 1) {
            float oA = __shfl_up(WA, d, 64);
            float oB = __shfl_up(WB, d, 64);
            if (lane >= d) { WA += oA; WB += oB; }
        }
        const float DxA = bD0 + (WA - qA3);
        const float DxB = bD1 + (WB - qB3);
        bD0 += __shfl(WA, 63, 64);
        bD1 += __shfl(WB, 63, 64);
        asd0 += (sqrtf(fmaxf((DxA + qA0) * rz0, 1e-12f)) +
                 sqrtf(fmaxf((DxA + qA1) * rz1, 1e-12f))) +
                (sqrtf(fmaxf((DxA + qA2) * rz2, 1e-12f)) +
                 sqrtf(fmaxf((DxA + qA3) * rz3, 1e-12f)));
        asd1 += (sqrtf(fmaxf((DxB + qB0) * rz0, 1e-12f)) +
                 sqrtf(fmaxf((DxB + qB1) * rz1, 1e-12f))) +
                (sqrtf(fmaxf((DxB + qB2) * rz2, 1e-12f)) +
                 sqrtf(fmaxf((DxB + qB3) * rz3, 1e-12f)));
    }
#pragma unroll
    for (int d = 1; d < 64; d <<= 1) {
        am0  += __shfl_xor(am0, d, 64);
        am1  += __shfl_xor(am1, d, 64);
        asd0 += __shfl_xor(asd0, d, 64);
        asd1 += __shfl_xor(asd1, d, 64);
    }
    if (lane == 0) {
        out[(size_t)b * (2 * C_) + c]          = am0  * (1.f / 4096.f);
        out[(size_t)b * (2 * C_) + c + 1]      = am1  * (1.f / 4096.f);
        out[(size_t)b * (2 * C_) + C_ + c]     = asd0 * (1.f / 4096.f);
        out[(size_t)b * (2 * C_) + C_ + c + 1] = asd1 * (1.f / 4096.f);
    }
}

extern "C" void kernel_launch(void* const* d_in, const int* in_sizes, int n_in,
                              void* d_out, int out_size, void* d_ws, size_t ws_size,
                              hipStream_t stream) {
    const float* x    = (const float*)d_in[0];
    const int*   lens = (const int*)d_in[1];
    const float* W1   = (const float*)d_in[2];
    const float* b1   = (const float*)d_in[3];
    const float* W2   = (const float*)d_in[4];
    float* out = (float*)d_out;
    char* ws = (char*)d_ws;

    // ws layout (~25.5 MB):
    float2*    carryT = (float2*)ws;                     // 8*256*1536*8 = 25,165,824
    _Float16*  W1f    = (_Float16*)(ws + 25165824);      //                1,179,648
    float*     logits = (float*)(ws + 26345472);         //                  131,072
    float*     earr   = (float*)(ws + 26476544);         //                  131,072
    float*     zarr   = (float*)(ws + 26607616);         //                  131,072

    k0_pack   <<<(A_ * K3_ + 255) / 256, 256, 0, stream>>>(W1, W1f);
    k1_carryT <<<(B_ * C_) / 8, 256, 0, stream>>>(x, lens, carryT);
    k2h       <<<B_ * 64, 256, 0, stream>>>(x, lens, carryT, W1f, b1, W2, logits);
    k3_softmax<<<B_, 1024, 0, stream>>>(logits, earr, zarr);
    k4_wstats <<<(B_ * C_) / 8, 256, 0, stream>>>(x, earr, zarr, out);
}

// Round 7
// 458.965 us; speedup vs baseline: 1.1487x; 1.1487x over previous
//
#include <hip/hip_runtime.h>
#include <hip/hip_bf16.h>

#define B_ 8
#define C_ 1536
#define T_ 4096
#define A_ 128
#define K3_ 4608        // 3*C columns of W1
#define M32_ 128        // T / 32 chunks (carry granularity)
#define SCW_ 104        // k2i scratch row stride (f16), 16B-aligned

typedef _Float16 h8  __attribute__((ext_vector_type(8)));
typedef float    f4  __attribute__((ext_vector_type(4)));

// ---------------- kernel 0: W1 fp32 -> f16, MFMA A-fragment order -----------
// W1f[((kb*8 + t8)*64 + lane)*8 + j] = W1[a=t8*16+(lane&15)][k=kb*32+(lane>>4)*8+j]
__global__ void k0_pack(const float* __restrict__ W1, _Float16* __restrict__ W1f) {
    int i = blockIdx.x * 256 + threadIdx.x;
    if (i >= A_ * K3_) return;
    int a = i / K3_, k = i - a * K3_;
    int t8 = a >> 4, r15 = a & 15;
    int kb = k >> 5, q = (k >> 3) & 3, j = k & 7;
    int lane = q * 16 + r15;
    W1f[(size_t)((kb * 8 + t8) * 64 + lane) * 8 + j] = (_Float16)W1[i];
}

// ---------------- kernel 1: 32-t-granular carries -> carryT[b][m][c] --------
// 2 rows per wave; coalesced float4 x loads; 32-t chunks = 8 lanes.
__global__ __launch_bounds__(256) void k1_carryT(
    const float* __restrict__ x, const int* __restrict__ lens,
    float2* __restrict__ carryT)
{
    const int pid  = blockIdx.x * 4 + (threadIdx.x >> 6);  // row-pair
    const int lane = threadIdx.x & 63;
    const int b    = pid / 768;
    const int c0   = (pid - b * 768) * 2;
    const int len  = lens[b];
    const float* xr0 = x + ((size_t)b * C_ + c0) * T_;
    const float* xr1 = xr0 + T_;
    float2* ct = carryT + (size_t)b * M32_ * C_ + c0;
    const int grp = lane >> 3;           // 32-t chunk 0..7 within 256-t g
    float bA1 = 0.f, bA2 = 0.f, bB1 = 0.f, bB2 = 0.f;
#pragma unroll
    for (int g = 0; g < 16; ++g) {
        const int t0g = g * 256;
        if (t0g >= len) {
            if ((lane & 7) == 0) {
                float4 st = {bA1, bA2, bB1, bB2};
                *(float4*)&ct[(size_t)(g * 8 + grp) * C_] = st;
            }
            continue;
        }
        float4 va = *(const float4*)(xr0 + t0g + lane * 4);
        float4 vb = *(const float4*)(xr1 + t0g + lane * 4);
        float sA1, sA2, sB1, sB2;
        if (t0g + 256 <= len) {
            sA1 = (va.x + va.y) + (va.z + va.w);
            sA2 = (va.x * va.x + va.y * va.y) + (va.z * va.z + va.w * va.w);
            sB1 = (vb.x + vb.y) + (vb.z + vb.w);
            sB2 = (vb.x * vb.x + vb.y * vb.y) + (vb.z * vb.z + vb.w * vb.w);
        } else {
            const int tbase = t0g + lane * 4;
            float av[4] = {va.x, va.y, va.z, va.w};
            float bv[4] = {vb.x, vb.y, vb.z, vb.w};
            sA1 = sA2 = sB1 = sB2 = 0.f;
#pragma unroll
            for (int j = 0; j < 4; ++j) {
                bool in = (tbase + j) < len;
                float ma = in ? av[j] : 0.f;
                float mb = in ? bv[j] : 0.f;
                sA1 += ma; sA2 += ma * av[j];
                sB1 += mb; sB2 += mb * bv[j];
            }
        }
        // 8-lane chunk totals
        sA1 += __shfl_xor(sA1, 1, 64); sA2 += __shfl_xor(sA2, 1, 64);
        sB1 += __shfl_xor(sB1, 1, 64); sB2 += __shfl_xor(sB2, 1, 64);
        sA1 += __shfl_xor(sA1, 2, 64); sA2 += __shfl_xor(sA2, 2, 64);
        sB1 += __shfl_xor(sB1, 2, 64); sB2 += __shfl_xor(sB2, 2, 64);
        sA1 += __shfl_xor(sA1, 4, 64); sA2 += __shfl_xor(sA2, 4, 64);
        sB1 += __shfl_xor(sB1, 4, 64); sB2 += __shfl_xor(sB2, 4, 64);
        // inclusive scan over 8 chunks (stride-8)
        float VA1 = sA1, VA2 = sA2, VB1 = sB1, VB2 = sB2;
#pragma unroll
        for (int d = 8; d < 64; d <<= 1) {
            float oA1 = __shfl_up(VA1, d, 64);
            float oA2 = __shfl_up(VA2, d, 64);
            float oB1 = __shfl_up(VB1, d, 64);
            float oB2 = __shfl_up(VB2, d, 64);
            if (lane >= d) { VA1 += oA1; VA2 += oA2; VB1 += oB1; VB2 += oB2; }
        }
        if ((lane & 7) == 0) {
            float4 st = {bA1 + VA1 - sA1, bA2 + VA2 - sA2,
                         bB1 + VB1 - sB1, bB2 + VB2 - sB2};
            *(float4*)&ct[(size_t)(g * 8 + grp) * C_] = st;
        }
        bA1 += __shfl(VA1, 63, 64);
        bA2 += __shfl(VA2, 63, 64);
        bB1 += __shfl(VB1, 63, 64);
        bB2 += __shfl(VB2, 63, 64);
    }
}

// ---------------- kernel 2i: fused stats+GEMM, 2xA x 2xK wave grid ----------
// grid 1024 = (b, 32-t chunk). 4 waves = (A-half ah) x (K-half kh).
// Wave: Nt=32 (block tile), 64 a, 24 c-steps. acc = 32 AGPR, body ~60 VGPR
// -> total <=128 -> 4 waves/SIMD at 4 blocks/CU = 16 waves/CU.
// Stats duplicated across ah twins (x loads L1-shared). Lane = (kc, th);
// th-interleaved 8-t octets keep only 8 xs live. Barrier-free main loop.
__global__ __launch_bounds__(256, 4) void k2i(
    const float* __restrict__ x, const int* __restrict__ lens,
    const float2* __restrict__ carryT, const _Float16* __restrict__ W1f,
    const float* __restrict__ b1, const float* __restrict__ W2,
    float* __restrict__ logits)
{
    __shared__ __align__(16) char smem[27648];   // 4x(32 x SCW_) f16 / 16KB red
    __shared__ float s_b1[A_], s_w2[A_];
    __shared__ float s_pr[2][32];

    const int tid = threadIdx.x, lane = tid & 63, w = tid >> 6;
    const int ah = w & 1;                // A-half (64 rows of W1)
    const int kh = w >> 1;               // K-half (768 channels)
    const int bid = blockIdx.x;
    const int b   = bid >> 7;
    const int m   = bid & 127;
    const int t0  = m << 5;
    const int len = lens[b];
    if (tid < A_) { s_b1[tid] = b1[tid]; s_w2[tid] = W2[tid]; }

    const int kc = lane >> 1;            // channel within 32-group
    const int th = lane & 1;             // octet-half owner
    _Float16* sc = (_Float16*)smem + w * (32 * SCW_);
    const int kcol = (((kc >> 3) ^ (th << 1)) << 3) + (kc & 7);
    _Float16* scw = sc + th * 8 * SCW_ + kcol;     // +oc*16*SCW_ per octet
    const h8* W1f8 = (const h8*)W1f;
    const int c_base = kh * 768;

    const bool beyond = t0 >= len;               // wave-uniform
    const bool full   = (t0 + 32) <= len;        // wave-uniform

    f4 acc[2][4] = {};                           // [nn 16-t][ii 16-a] = 32 AGPR
    const float* xptr = x + ((size_t)b * C_ + c_base + kc) * T_ + t0 + th * 8;
    const float2* crp = carryT + ((size_t)b * M32_ + m) * C_ + c_base + kc;

    const int t15 = lane & 15, k8 = lane >> 4;
    const int rdbase = t15 * SCW_ + ((k8 ^ ((t15 >> 3) << 1)) << 3);

    for (int step = 0; step < 24; ++step) {
        const float2 cr = crp[(size_t)step * 32];
        float base1 = cr.x, base2 = cr.y;
#pragma unroll
        for (int oc = 0; oc < 2; ++oc) {
            // lane's octet: t = t0 + oc*16 + th*8 + j
            const int tb = t0 + oc * 16 + th * 8;
            float xs[8];
            *(float4*)&xs[0] = ((const float4*)(xptr + oc * 16))[0];
            *(float4*)&xs[4] = ((const float4*)(xptr + oc * 16))[1];
            _Float16* scwo = scw + oc * 16 * SCW_;
            if (beyond) {
                const float rn0 = __builtin_amdgcn_rcpf((float)len);
                const float mn = base1 * rn0;
                const float sd = sqrtf(fmaxf(base2 * rn0 - mn * mn, 1e-12f));
                const _Float16 hm = (_Float16)mn, hs = (_Float16)sd;
#pragma unroll
                for (int j = 0; j < 8; ++j) {
                    scwo[j * SCW_]      = (_Float16)xs[j];
                    scwo[j * SCW_ + 32] = hm;
                    scwo[j * SCW_ + 64] = hs;
                }
            } else {
                float ls1 = 0.f, ls2 = 0.f;
                if (full) {
#pragma unroll
                    for (int j = 0; j < 8; ++j) { ls1 += xs[j]; ls2 += xs[j] * xs[j]; }
                } else {
#pragma unroll
                    for (int j = 0; j < 8; ++j) {
                        float mv = (tb + j < len) ? xs[j] : 0.f;
                        ls1 += mv; ls2 += mv * xs[j];
                    }
                }
                const float o1 = __shfl_xor(ls1, 1, 64);
                const float o2 = __shfl_xor(ls2, 1, 64);
                float r1 = base1 + (th ? o1 : 0.f);
                float r2 = base2 + (th ? o2 : 0.f);
#pragma unroll
                for (int j = 0; j < 8; ++j) {
                    const float xval = xs[j];
                    const float mv = (full || (tb + j < len)) ? xval : 0.f;
                    r1 += mv; r2 += mv * xval;
                    const float rn = __builtin_amdgcn_rcpf((float)min(tb + j + 1, len));
                    const float mn = r1 * rn;
                    const float sd = sqrtf(fmaxf(r2 * rn - mn * mn, 1e-12f));
                    scwo[j * SCW_]      = (_Float16)xval;
                    scwo[j * SCW_ + 32] = (_Float16)mn;
                    scwo[j * SCW_ + 64] = (_Float16)sd;
                }
                base1 += ls1 + o1;               // both octet totals
                base2 += ls2 + o2;
            }
        }
        xptr += 32 * (size_t)T_;
        // within-wave LDS ordering via lgkmcnt; no barrier needed
        const int kb0 = kh * 24 + step;
#pragma unroll
        for (int p = 0; p < 3; ++p) {
            h8 bf0 = *(const h8*)&sc[rdbase + p * 32];
            h8 bf1 = *(const h8*)&sc[rdbase + 16 * SCW_ + p * 32];
            const int kb = p * 48 + kb0;
#pragma unroll
            for (int ii = 0; ii < 4; ++ii) {
                h8 af = W1f8[(size_t)(kb * 8 + ah * 4 + ii) * 64 + lane];
                acc[0][ii] = __builtin_amdgcn_mfma_f32_16x16x32_f16(af, bf0, acc[0][ii], 0, 0, 0);
                acc[1][ii] = __builtin_amdgcn_mfma_f32_16x16x32_f16(af, bf1, acc[1][ii], 0, 0, 0);
            }
        }
    }

    // ---- epilogue: kh-pair reduce, tanh+W2, cross-ah sum (3 barriers) ----
    __syncthreads();
    float* red = (float*)smem;
    if (kh == 1) {
        float* r = red + ah * 2048;
#pragma unroll
        for (int nn = 0; nn < 2; ++nn)
#pragma unroll
            for (int ii = 0; ii < 4; ++ii)
#pragma unroll
                for (int rg = 0; rg < 4; ++rg)
                    r[((nn * 4 + ii) * 4 + rg) * 64 + lane] = acc[nn][ii][rg];
    }
    __syncthreads();
    if (kh == 0) {
        float* r = red + ah * 2048;
        const int q = lane >> 4;
#pragma unroll
        for (int nn = 0; nn < 2; ++nn) {
            float pr = 0.f;
#pragma unroll
            for (int ii = 0; ii < 4; ++ii)
#pragma unroll
                for (int rg = 0; rg < 4; ++rg) {
                    float v = acc[nn][ii][rg] + r[((nn * 4 + ii) * 4 + rg) * 64 + lane];
                    const int a = ah * 64 + ii * 16 + q * 4 + rg;
                    pr += tanhf(v + s_b1[a]) * s_w2[a];
                }
            pr += __shfl_xor(pr, 16, 64);
            pr += __shfl_xor(pr, 32, 64);
            if (lane < 16) s_pr[ah][nn * 16 + lane] = pr;
        }
    }
    __syncthreads();
    if (tid < 32)
        logits[(size_t)b * T_ + t0 + tid] = s_pr[0][tid] + s_pr[1][tid];
}

// ---------------- kernel 3: softmax prep (e, cumsum Z) per b ----------------
// b2 and the max-subtraction cancel in the e/Z ratios used downstream.
__global__ __launch_bounds__(1024) void k3_softmax(
    const float* __restrict__ logits, float* __restrict__ earr,
    float* __restrict__ zarr)
{
    __shared__ float wsum[16];
    const int b = blockIdx.x, tid = threadIdx.x, lane = tid & 63, w = tid >> 6;
    float4 v = *(const float4*)(logits + (size_t)b * T_ + tid * 4);
    float e0 = expf(v.x), e1 = expf(v.y), e2 = expf(v.z), e3 = expf(v.w);
    float s = (e0 + e1) + (e2 + e3);
    float V = s;
#pragma unroll
    for (int d = 1; d < 64; d <<= 1) {
        float o = __shfl_up(V, d, 64);
        if (lane >= d) V += o;
    }
    if (lane == 63) wsum[w] = V;
    __syncthreads();
    float wb = 0.f;
#pragma unroll
    for (int i = 0; i < 16; ++i) wb += (i < w) ? wsum[i] : 0.f;
    float run = wb + (V - s);
    float4 ev, zv;
    ev.x = e0; run += e0; zv.x = run;
    ev.y = e1; run += e1; zv.y = run;
    ev.z = e2; run += e2; zv.z = run;
    ev.w = e3; run += e3; zv.w = run;
    *(float4*)(earr + (size_t)b * T_ + tid * 4) = ev;
    *(float4*)(zarr + (size_t)b * T_ + tid * 4) = zv;
}

// ---------------- kernel 4: weighted running mean/std, 2 rows/wave ----------
__global__ __launch_bounds__(256) void k4_wstats(
    const float* __restrict__ x, const float* __restrict__ earr,
    const float* __restrict__ zarr, float* __restrict__ out)
{
    const int pid  = blockIdx.x * 4 + (threadIdx.x >> 6);  // row-pair
    const int lane = threadIdx.x & 63;
    const int b = pid / 768;
    const int c = (pid - b * 768) * 2;
    const float* xr0 = x + ((size_t)b * C_ + c) * T_;
    const float* xr1 = xr0 + T_;
    const float* er = earr + (size_t)b * T_;
    const float* zr = zarr + (size_t)b * T_;
    float am0 = 0.f, asd0 = 0.f, am1 = 0.f, asd1 = 0.f;
    float bS0 = 0.f, bD0 = 0.f, bS1 = 0.f, bD1 = 0.f;
#pragma unroll 4
    for (int g = 0; g < 16; ++g) {
        const int off = g * 256 + lane * 4;
        float4 ev = *(const float4*)(er + off);
        float4 zv = *(const float4*)(zr + off);
        float4 xa = *(const float4*)(xr0 + off);
        float4 xb = *(const float4*)(xr1 + off);
        float sA0 = ev.x * xa.x;
        float sA1 = sA0 + ev.y * xa.y;
        float sA2 = sA1 + ev.z * xa.z;
        float sA3 = sA2 + ev.w * xa.w;
        float sB0 = ev.x * xb.x;
        float sB1 = sB0 + ev.y * xb.y;
        float sB2 = sB1 + ev.z * xb.z;
        float sB3 = sB2 + ev.w * xb.w;
        float VA = sA3, VB = sB3;
#pragma unroll
        for (int d = 1; d < 64; d <<= 1) {
            float oA = __shfl_up(VA, d, 64);
            float oB = __shfl_up(VB, d, 64);
            if (lane >= d) { VA += oA; VB += oB; }
        }
        const float SxA = bS0 + (VA - sA3);
        const float SxB = bS1 + (VB - sB3);
        bS0 += __shfl(VA, 63, 64);
        bS1 += __shfl(VB, 63, 64);
        const float rz0 = __builtin_amdgcn_rcpf(zv.x);
        const float rz1 = __builtin_amdgcn_rcpf(zv.y);
        const float rz2 = __builtin_amdgcn_rcpf(zv.z);
        const float rz3 = __builtin_amdgcn_rcpf(zv.w);
        const float wmA0 = (SxA + sA0) * rz0, wmA1 = (SxA + sA1) * rz1;
        const float wmA2 = (SxA + sA2) * rz2, wmA3 = (SxA + sA3) * rz3;
        const float wmB0 = (SxB + sB0) * rz0, wmB1 = (SxB + sB1) * rz1;
        const float wmB2 = (SxB + sB2) * rz2, wmB3 = (SxB + sB3) * rz3;
        am0 += (wmA0 + wmA1) + (wmA2 + wmA3);
        am1 += (wmB0 + wmB1) + (wmB2 + wmB3);
        const float dA0 = xa.x - wmA0, dA1 = xa.y - wmA1;
        const float dA2 = xa.z - wmA2, dA3 = xa.w - wmA3;
        const float dB0 = xb.x - wmB0, dB1 = xb.y - wmB1;
        const float dB2 = xb.z - wmB2, dB3 = xb.w - wmB3;
        float qA0 = ev.x * dA0 * dA0;
        float qA1 = qA0 + ev.y * dA1 * dA1;
        float qA2 = qA1 + ev.z * dA2 * dA2;
        float qA3 = qA2 + ev.w * dA3 * dA3;
        float qB0 = ev.x * dB0 * dB0;
        float qB1 = qB0 + ev.y * dB1 * dB1;
        float qB2 = qB1 + ev.z * dB2 * dB2;
        float qB3 = qB2 + ev.w * dB3 * dB3;
        float WA = qA3, WB = qB3;
#pragma unroll
        for (int d = 1; d < 64; d <<= 1) {
            float oA = __shfl_up(WA, d, 64);
            float oB = __shfl_up(WB, d, 64);
            if (lane >= d) { WA += oA; WB += oB; }
        }
        const float DxA = bD0 + (WA - qA3);
        const float DxB = bD1 + (WB - qB3);
        bD0 += __shfl(WA, 63, 64);
        bD1 += __shfl(WB, 63, 64);
        asd0 += (sqrtf(fmaxf((DxA + qA0) * rz0, 1e-12f)) +
                 sqrtf(fmaxf((DxA + qA1) * rz1, 1e-12f))) +
                (sqrtf(fmaxf((DxA + qA2) * rz2, 1e-12f)) +
                 sqrtf(fmaxf((DxA + qA3) * rz3, 1e-12f)));
        asd1 += (sqrtf(fmaxf((DxB + qB0) * rz0, 1e-12f)) +
                 sqrtf(fmaxf((DxB + qB1) * rz1, 1e-12f))) +
                (sqrtf(fmaxf((DxB + qB2) * rz2, 1e-12f)) +
                 sqrtf(fmaxf((DxB + qB3) * rz3, 1e-12f)));
    }
#pragma unroll
    for (int d = 1; d < 64; d <<= 1) {
        am0  += __shfl_xor(am0, d, 64);
        am1  += __shfl_xor(am1, d, 64);
        asd0 += __shfl_xor(asd0, d, 64);
        asd1 += __shfl_xor(asd1, d, 64);
    }
    if (lane == 0) {
        out[(size_t)b * (2 * C_) + c]          = am0  * (1.f / 4096.f);
        out[(size_t)b * (2 * C_) + c + 1]      = am1  * (1.f / 4096.f);
        out[(size_t)b * (2 * C_) + C_ + c]     = asd0 * (1.f / 4096.f);
        out[(size_t)b * (2 * C_) + C_ + c + 1] = asd1 * (1.f / 4096.f);
    }
}

extern "C" void kernel_launch(void* const* d_in, const int* in_sizes, int n_in,
                              void* d_out, int out_size, void* d_ws, size_t ws_size,
                              hipStream_t stream) {
    const float* x    = (const float*)d_in[0];
    const int*   lens = (const int*)d_in[1];
    const float* W1   = (const float*)d_in[2];
    const float* b1   = (const float*)d_in[3];
    const float* W2   = (const float*)d_in[4];
    float* out = (float*)d_out;
    char* ws = (char*)d_ws;

    // ws layout (~14.2 MB):
    float2*    carryT = (float2*)ws;                     // 8*128*1536*8 = 12,582,912
    _Float16*  W1f    = (_Float16*)(ws + 12582912);      //                1,179,648
    float*     logits = (float*)(ws + 13762560);         //                  131,072
    float*     earr   = (float*)(ws + 13893632);         //                  131,072
    float*     zarr   = (float*)(ws + 14024704);         //                  131,072

    k0_pack   <<<(A_ * K3_ + 255) / 256, 256, 0, stream>>>(W1, W1f);
    k1_carryT <<<(B_ * C_) / 8, 256, 0, stream>>>(x, lens, carryT);
    k2i       <<<B_ * M32_, 256, 0, stream>>>(x, lens, carryT, W1f, b1, W2, logits);
    k3_softmax<<<B_, 1024, 0, stream>>>(logits, earr, zarr);
    k4_wstats <<<(B_ * C_) / 8, 256, 0, stream>>>(x, earr, zarr, out);
}